// Round 2
// baseline (373.692 us; speedup 1.0000x reference)
//
#include <hip/hip_runtime.h>

typedef __attribute__((ext_vector_type(8))) short short8;
typedef __attribute__((ext_vector_type(4))) float f32x4;

__device__ __forceinline__ unsigned short f2bf(float f) {
  unsigned int u = __float_as_uint(f);
  u += 0x7fffu + ((u >> 16) & 1u);   // round-to-nearest-even
  return (unsigned short)(u >> 16);
}
__device__ __forceinline__ float bf2f(unsigned short h) {
  return __uint_as_float(((unsigned int)h) << 16);
}
__device__ __forceinline__ unsigned int pkbf(float a, float b) {
  return (unsigned int)f2bf(a) | ((unsigned int)f2bf(b) << 16);
}
__device__ __forceinline__ short8 ld8(const unsigned short* p) {
  return *(const short8*)p;
}
#define MFMA(a, b, c) __builtin_amdgcn_mfma_f32_16x16x32_bf16((a), (b), (c), 0, 0, 0)
#define LOG2E 1.4426950408889634f

// ---------------------------------------------------------------------------
// Kernel 1: weight prep. Wcat^T hi/lo bf16 [192][256] (rows 0-31 Wq^T, 32-63
// Wk^T, 64-191 Wv^T), WoT bf16 [256][128].
// ---------------------------------------------------------------------------
__global__ void prep_weights(const float* __restrict__ Wq, const float* __restrict__ Wk,
                             const float* __restrict__ Wv, const float* __restrict__ Wo,
                             unsigned short* __restrict__ Wth, unsigned short* __restrict__ Wtl,
                             unsigned short* __restrict__ WoT) {
  int idx = blockIdx.x * 256 + threadIdx.x;
  if (idx < 192 * 256) {
    int o = idx >> 8, c = idx & 255;
    float w = (o < 32) ? Wq[c * 32 + o] : (o < 64) ? Wk[c * 32 + (o - 32)] : Wv[c * 128 + (o - 64)];
    unsigned short h = f2bf(w);
    Wth[idx] = h;
    Wtl[idx] = f2bf(w - bf2f(h));
  } else if (idx < 192 * 256 + 256 * 128) {
    int j = idx - 192 * 256;
    int c = j >> 7, d = j & 127;
    WoT[j] = f2bf(Wo[d * 256 + c]);
  }
}

// ---------------------------------------------------------------------------
// Kernel 2: QKV projection. 32 pixels/block. q is pre-scaled by log2(e) so the
// flash kernel can use raw v_exp_f32 (exp2) for softmax.
// ---------------------------------------------------------------------------
__global__ __launch_bounds__(256) void proj_qkv(
    const float* __restrict__ x,
    const unsigned short* __restrict__ Wth, const unsigned short* __restrict__ Wtl,
    const float* __restrict__ bq, const float* __restrict__ bk, const float* __restrict__ bv,
    unsigned short* __restrict__ qh, unsigned short* __restrict__ qlo,
    unsigned short* __restrict__ kh, unsigned short* __restrict__ klo,
    unsigned short* __restrict__ Vt) {
  __shared__ unsigned short xsh[32][264];
  __shared__ unsigned short xsl[32][264];
  const int pix0 = blockIdx.x * 32;
  const int b = pix0 >> 12;
  const int nloc0 = pix0 & 4095;
  const int tid = threadIdx.x;

#pragma unroll
  for (int i = 0; i < 8; ++i) {
    int chunk = i * 256 + tid;
    int row = chunk >> 6;
    int c4 = (chunk & 63) * 4;
    float4 v = *(const float4*)(x + (size_t)(pix0 + row) * 256 + c4);
    unsigned short h0 = f2bf(v.x), h1 = f2bf(v.y), h2 = f2bf(v.z), h3 = f2bf(v.w);
    unsigned short l0 = f2bf(v.x - bf2f(h0)), l1 = f2bf(v.y - bf2f(h1));
    unsigned short l2 = f2bf(v.z - bf2f(h2)), l3 = f2bf(v.w - bf2f(h3));
    uint2 hp, lp;
    hp.x = (unsigned int)h0 | ((unsigned int)h1 << 16);
    hp.y = (unsigned int)h2 | ((unsigned int)h3 << 16);
    lp.x = (unsigned int)l0 | ((unsigned int)l1 << 16);
    lp.y = (unsigned int)l2 | ((unsigned int)l3 << 16);
    *(uint2*)&xsh[row][c4] = hp;
    *(uint2*)&xsl[row][c4] = lp;
  }
  __syncthreads();

  const int wave = tid >> 6, lane = tid & 63, l = lane & 15, qd = lane >> 4;
#pragma unroll
  for (int si = 0; si < 3; ++si) {
    const int sub = wave + si * 4;
    const int outc0 = sub * 16;
    if (si == 0) {  // q/k, split precision
      const int outc = outc0 + l;
      const float bias = (outc < 32) ? bq[outc] : bk[outc - 32];
      f32x4 acc[2];
      acc[0] = (f32x4){bias, bias, bias, bias};
      acc[1] = (f32x4){bias, bias, bias, bias};
#pragma unroll
      for (int kc = 0; kc < 8; ++kc) {
        short8 whf = ld8(Wth + (size_t)(outc0 + l) * 256 + kc * 32 + qd * 8);
        short8 wlf = ld8(Wtl + (size_t)(outc0 + l) * 256 + kc * 32 + qd * 8);
#pragma unroll
        for (int m = 0; m < 2; ++m) {
          short8 xhf = ld8(&xsh[m * 16 + l][kc * 32 + qd * 8]);
          short8 xlf = ld8(&xsl[m * 16 + l][kc * 32 + qd * 8]);
          acc[m] = MFMA(xlf, whf, acc[m]);
          acc[m] = MFMA(xhf, wlf, acc[m]);
          acc[m] = MFMA(xhf, whf, acc[m]);
        }
      }
#pragma unroll
      for (int m = 0; m < 2; ++m)
#pragma unroll
        for (int r = 0; r < 4; ++r) {
          const size_t pixel = (size_t)pix0 + m * 16 + 4 * qd + r;
          float val = acc[m][r];
          if (outc < 32) val *= LOG2E;   // exp2-domain softmax
          unsigned short h = f2bf(val);
          unsigned short lo = f2bf(val - bf2f(h));
          if (outc < 32) { qh[pixel * 32 + outc] = h; qlo[pixel * 32 + outc] = lo; }
          else           { kh[pixel * 32 + outc - 32] = h; klo[pixel * 32 + outc - 32] = lo; }
        }
    } else {  // v, transposed output
      const int dv0 = outc0 - 64;
      const float b0 = bv[dv0 + 4 * qd + 0], b1 = bv[dv0 + 4 * qd + 1];
      const float b2 = bv[dv0 + 4 * qd + 2], b3 = bv[dv0 + 4 * qd + 3];
      f32x4 acc[2];
      acc[0] = (f32x4){b0, b1, b2, b3};
      acc[1] = (f32x4){b0, b1, b2, b3};
#pragma unroll
      for (int kc = 0; kc < 8; ++kc) {
        short8 whf = ld8(Wth + (size_t)(outc0 + l) * 256 + kc * 32 + qd * 8);
#pragma unroll
        for (int m = 0; m < 2; ++m) {
          short8 xhf = ld8(&xsh[m * 16 + l][kc * 32 + qd * 8]);
          acc[m] = MFMA(whf, xhf, acc[m]);  // D = Wv^T * x^T  -> Vt layout
        }
      }
#pragma unroll
      for (int m = 0; m < 2; ++m)
#pragma unroll
        for (int r = 0; r < 4; ++r) {
          int dv = dv0 + 4 * qd + r;
          int n = nloc0 + m * 16 + l;
          Vt[(size_t)b * 128 * 4096 + (size_t)dv * 4096 + n] = f2bf(acc[m][r]);
        }
    }
  }
}

// ---------------------------------------------------------------------------
// Kernel 3: flash attention, SPLIT-K x4. 1024 blocks (batch=blockIdx&7 ->
// XCD-pinned L2; split/tile from upper bits). Each block handles 128 queries
// x 1024 keys. Writes unnormalized O-partials (bf16) into d_out used as
// scratch, plus per-row (m,l) stats. exp2-domain (q pre-scaled by log2e).
// P packed to bf16 BEFORE shuffling: 32 bpermutes/iter instead of 64.
// ---------------------------------------------------------------------------
__global__ __launch_bounds__(256, 4) void flash_attn(
    const unsigned short* __restrict__ qh, const unsigned short* __restrict__ qlo,
    const unsigned short* __restrict__ kh, const unsigned short* __restrict__ klo,
    const unsigned short* __restrict__ Vt, unsigned short* __restrict__ opart,
    float* __restrict__ mstat, float* __restrict__ lstat) {
  const int b = blockIdx.x & 7;
  const int r7 = blockIdx.x >> 3;      // 0..127
  const int tile = r7 & 31;            // 0..31
  const int split = r7 >> 5;           // 0..3
  const int wave = threadIdx.x >> 6;
  const int lane = threadIdx.x & 63;
  const int l = lane & 15;
  const int qd = lane >> 4;
  const int m0 = tile * 128 + wave * 32;
  const unsigned short* qh_b = qh + (size_t)b * 4096 * 32;
  const unsigned short* ql_b = qlo + (size_t)b * 4096 * 32;
  const unsigned short* kh_b = kh + (size_t)b * 4096 * 32;
  const unsigned short* kl_b = klo + (size_t)b * 4096 * 32;
  const unsigned short* vt_b = Vt + (size_t)b * 128 * 4096;

  short8 qhf[2], qlf[2];
#pragma unroll
  for (int t = 0; t < 2; ++t) {
    int row = m0 + t * 16 + l;
    qhf[t] = ld8(qh_b + (size_t)row * 32 + qd * 8);
    qlf[t] = ld8(ql_b + (size_t)row * 32 + qd * 8);
  }
  f32x4 acc[2][8];
#pragma unroll
  for (int t = 0; t < 2; ++t)
#pragma unroll
    for (int s = 0; s < 8; ++s) acc[t][s] = (f32x4){0.f, 0.f, 0.f, 0.f};
  float mrun[2] = {-1e30f, -1e30f};
  float lrun[2] = {0.f, 0.f};

  const int srcA = ((qd & 1) * 2) * 16 + l;
  const int srcB = srcA + 16;
  const bool hisel = (qd >> 1) != 0;

#pragma unroll 1
  for (int it = 0; it < 16; ++it) {
    const int n0 = split * 1024 + it * 64;
    short8 khf[4], klf[4];
#pragma unroll
    for (int s = 0; s < 4; ++s) {
      int row = n0 + s * 16 + l;
      khf[s] = ld8(kh_b + (size_t)row * 32 + qd * 8);
      klf[s] = ld8(kl_b + (size_t)row * 32 + qd * 8);
    }
    short8 pfrag[2][2];
#pragma unroll
    for (int t = 0; t < 2; ++t) {
      f32x4 s4[4];
#pragma unroll
      for (int s = 0; s < 4; ++s) {
        f32x4 z = (f32x4){0.f, 0.f, 0.f, 0.f};
        z = MFMA(klf[s], qhf[t], z);   // k_lo * q_hi
        z = MFMA(khf[s], qlf[t], z);   // k_hi * q_lo
        z = MFMA(khf[s], qhf[t], z);   // k_hi * q_hi
        s4[s] = z;                     // S^T: lane holds (n = n0+s*16+4qd+r, m = l)
      }
      float mx = -1e30f;
#pragma unroll
      for (int s = 0; s < 4; ++s)
#pragma unroll
        for (int r = 0; r < 4; ++r) mx = fmaxf(mx, s4[s][r]);
      mx = fmaxf(mx, __shfl_xor(mx, 16));
      mx = fmaxf(mx, __shfl_xor(mx, 32));
      const float mnew = fmaxf(mrun[t], mx);
      float rs = 0.f;
      unsigned int pp[4][2];
#pragma unroll
      for (int s = 0; s < 4; ++s) {
        float p0 = __builtin_amdgcn_exp2f(s4[s][0] - mnew);
        float p1 = __builtin_amdgcn_exp2f(s4[s][1] - mnew);
        float p2 = __builtin_amdgcn_exp2f(s4[s][2] - mnew);
        float p3 = __builtin_amdgcn_exp2f(s4[s][3] - mnew);
        rs += (p0 + p1) + (p2 + p3);
        pp[s][0] = pkbf(p0, p1);
        pp[s][1] = pkbf(p2, p3);
      }
      rs += __shfl_xor(rs, 16);
      rs += __shfl_xor(rs, 32);
      const float alpha = __builtin_amdgcn_exp2f(mrun[t] - mnew);
      lrun[t] = lrun[t] * alpha + rs;
      mrun[t] = mnew;
#pragma unroll
      for (int s = 0; s < 8; ++s)
#pragma unroll
        for (int r = 0; r < 4; ++r) acc[t][s][r] *= alpha;
      // Assemble P^T B-frags: lane needs P(m=l, key=32c+qd*8+j), packed bf16x2.
#pragma unroll
      for (int c = 0; c < 2; ++c) {
        unsigned int a00 = (unsigned int)__shfl((int)pp[2 * c][0], srcA);
        unsigned int a01 = (unsigned int)__shfl((int)pp[2 * c][1], srcA);
        unsigned int b00 = (unsigned int)__shfl((int)pp[2 * c + 1][0], srcA);
        unsigned int b01 = (unsigned int)__shfl((int)pp[2 * c + 1][1], srcA);
        unsigned int a10 = (unsigned int)__shfl((int)pp[2 * c][0], srcB);
        unsigned int a11 = (unsigned int)__shfl((int)pp[2 * c][1], srcB);
        unsigned int b10 = (unsigned int)__shfl((int)pp[2 * c + 1][0], srcB);
        unsigned int b11 = (unsigned int)__shfl((int)pp[2 * c + 1][1], srcB);
        union { unsigned int u[4]; short8 v; } cv;
        cv.u[0] = hisel ? b00 : a00;
        cv.u[1] = hisel ? b01 : a01;
        cv.u[2] = hisel ? b10 : a10;
        cv.u[3] = hisel ? b11 : a11;
        pfrag[t][c] = cv.v;
      }
    }
#pragma unroll
    for (int s = 0; s < 8; ++s) {
      const unsigned short* vr = vt_b + (size_t)(s * 16 + l) * 4096 + n0 + qd * 8;
      short8 v0 = ld8(vr);
      short8 v1 = ld8(vr + 32);
      acc[0][s] = MFMA(v0, pfrag[0][0], acc[0][s]);
      acc[0][s] = MFMA(v1, pfrag[0][1], acc[0][s]);
      acc[1][s] = MFMA(v0, pfrag[1][0], acc[1][s]);
      acc[1][s] = MFMA(v1, pfrag[1][1], acc[1][s]);
    }
  }
  // Epilogue: unnormalized partials + stats.
#pragma unroll
  for (int t = 0; t < 2; ++t) {
    const int row = b * 4096 + m0 + t * 16 + l;
    const size_t obase = ((size_t)split * 32768 + row) * 128;
#pragma unroll
    for (int s = 0; s < 8; ++s) {
      uint2 pkt;
      pkt.x = pkbf(acc[t][s][0], acc[t][s][1]);
      pkt.y = pkbf(acc[t][s][2], acc[t][s][3]);
      *(uint2*)(opart + obase + s * 16 + qd * 4) = pkt;
    }
    if (qd == 0) {
      mstat[split * 32768 + row] = mrun[t];
      lstat[split * 32768 + row] = lrun[t];
    }
  }
}

// ---------------------------------------------------------------------------
// Kernel 3b: combine split-K partials -> normalized attn output ao (bf16).
// ---------------------------------------------------------------------------
__global__ __launch_bounds__(256) void combine_splits(
    const unsigned short* __restrict__ opart, const float* __restrict__ mstat,
    const float* __restrict__ lstat, unsigned short* __restrict__ ao) {
  const int tid = threadIdx.x;
  const int row = blockIdx.x * 16 + (tid >> 4);
  const int col = (tid & 15) * 8;
  float m0 = mstat[row], m1 = mstat[32768 + row];
  float m2 = mstat[65536 + row], m3 = mstat[98304 + row];
  float M = fmaxf(fmaxf(m0, m1), fmaxf(m2, m3));
  float w[4];
  w[0] = __builtin_amdgcn_exp2f(m0 - M);
  w[1] = __builtin_amdgcn_exp2f(m1 - M);
  w[2] = __builtin_amdgcn_exp2f(m2 - M);
  w[3] = __builtin_amdgcn_exp2f(m3 - M);
  float den = w[0] * lstat[row] + w[1] * lstat[32768 + row] +
              w[2] * lstat[65536 + row] + w[3] * lstat[98304 + row];
  float inv = 1.f / den;
  float o[8] = {0.f, 0.f, 0.f, 0.f, 0.f, 0.f, 0.f, 0.f};
#pragma unroll
  for (int s = 0; s < 4; ++s) {
    uint4 v = *(const uint4*)(opart + ((size_t)s * 32768 + row) * 128 + col);
    unsigned int uu[4] = {v.x, v.y, v.z, v.w};
#pragma unroll
    for (int j = 0; j < 4; ++j) {
      o[2 * j]     += w[s] * bf2f((unsigned short)(uu[j] & 0xffff));
      o[2 * j + 1] += w[s] * bf2f((unsigned short)(uu[j] >> 16));
    }
  }
  uint4 outv;
  outv.x = pkbf(o[0] * inv, o[1] * inv);
  outv.y = pkbf(o[2] * inv, o[3] * inv);
  outv.z = pkbf(o[4] * inv, o[5] * inv);
  outv.w = pkbf(o[6] * inv, o[7] * inv);
  *(uint4*)(ao + (size_t)row * 128 + col) = outv;
}

// ---------------------------------------------------------------------------
// Kernel 4: output projection + bias + residual. out = ao @ Wo + bo + x.
// ---------------------------------------------------------------------------
__global__ __launch_bounds__(256) void out_proj(
    const unsigned short* __restrict__ ao, const unsigned short* __restrict__ WoT,
    const float* __restrict__ bo, const float* __restrict__ x, float* __restrict__ out) {
  const int pix0 = blockIdx.x * 64;
  const int wave = threadIdx.x >> 6, lane = threadIdx.x & 63, l = lane & 15, qd = lane >> 4;
  const int base = pix0 + wave * 16;
  short8 af[4];
#pragma unroll
  for (int kc = 0; kc < 4; ++kc)
    af[kc] = ld8(ao + (size_t)(base + l) * 128 + kc * 32 + qd * 8);
#pragma unroll
  for (int sub = 0; sub < 16; ++sub) {
    const int c = sub * 16 + l;
    const float bias = bo[c];
    f32x4 acc = (f32x4){bias, bias, bias, bias};
#pragma unroll
    for (int kc = 0; kc < 4; ++kc) {
      short8 wf = ld8(WoT + (size_t)c * 128 + kc * 32 + qd * 8);
      acc = MFMA(af[kc], wf, acc);
    }
#pragma unroll
    for (int r = 0; r < 4; ++r) {
      const size_t pixel = (size_t)base + 4 * qd + r;
      out[pixel * 256 + c] = acc[r] + x[pixel * 256 + c];
    }
  }
}

// ---------------------------------------------------------------------------
extern "C" void kernel_launch(void* const* d_in, const int* in_sizes, int n_in,
                              void* d_out, int out_size, void* d_ws, size_t ws_size,
                              hipStream_t stream) {
  const float* x  = (const float*)d_in[0];
  const float* Wq = (const float*)d_in[1];
  const float* bq = (const float*)d_in[2];
  const float* Wk = (const float*)d_in[3];
  const float* bk = (const float*)d_in[4];
  const float* Wv = (const float*)d_in[5];
  const float* bv = (const float*)d_in[6];
  const float* Wo = (const float*)d_in[7];
  const float* bo = (const float*)d_in[8];

  char* ws = (char*)d_ws;
  // Workspace map (bytes): total ~25.6 MB
  unsigned short* qh  = (unsigned short*)(ws + 0);          // 2 MB
  unsigned short* qlo = (unsigned short*)(ws + 2097152);    // 2 MB
  unsigned short* kh  = (unsigned short*)(ws + 4194304);    // 2 MB
  unsigned short* klo = (unsigned short*)(ws + 6291456);    // 2 MB
  unsigned short* Vt  = (unsigned short*)(ws + 8388608);    // 8 MB  [8][128][4096]
  unsigned short* ao  = (unsigned short*)(ws + 16777216);   // 8 MB  [32768][128]
  unsigned short* Wth = (unsigned short*)(ws + 25165824);   // 96 KB [192][256]
  unsigned short* Wtl = (unsigned short*)(ws + 25264128);   // 96 KB
  unsigned short* WoT = (unsigned short*)(ws + 25362432);   // 64 KB [256][128]
  float*          mst = (float*)(ws + 25493504);            // 512 KB [4][32768]
  float*          lst = (float*)(ws + 26017792);            // 512 KB [4][32768]
  // O-partials live in d_out used as scratch: [4][32768][128] bf16 = 32 MB,
  // fully overwritten by out_proj at the end (stream-ordered).
  unsigned short* opart = (unsigned short*)d_out;

  prep_weights<<<320, 256, 0, stream>>>(Wq, Wk, Wv, Wo, Wth, Wtl, WoT);
  proj_qkv<<<1024, 256, 0, stream>>>(x, Wth, Wtl, bq, bk, bv, qh, qlo, kh, klo, Vt);
  flash_attn<<<1024, 256, 0, stream>>>(qh, qlo, kh, klo, Vt, opart, mst, lst);
  combine_splits<<<2048, 256, 0, stream>>>(opart, mst, lst, ao);
  out_proj<<<512, 256, 0, stream>>>(ao, WoT, bo, x, (float*)d_out);
}

// Round 3
// 290.996 us; speedup vs baseline: 1.2842x; 1.2842x over previous
//
#include <hip/hip_runtime.h>

typedef __attribute__((ext_vector_type(8))) short short8;
typedef __attribute__((ext_vector_type(4))) float f32x4;

__device__ __forceinline__ unsigned short f2bf(float f) {
  unsigned int u = __float_as_uint(f);
  u += 0x7fffu + ((u >> 16) & 1u);   // round-to-nearest-even
  return (unsigned short)(u >> 16);
}
__device__ __forceinline__ float bf2f(unsigned short h) {
  return __uint_as_float(((unsigned int)h) << 16);
}
__device__ __forceinline__ unsigned int pkbf(float a, float b) {
  return (unsigned int)f2bf(a) | ((unsigned int)f2bf(b) << 16);
}
__device__ __forceinline__ short8 ld8(const unsigned short* p) {
  return *(const short8*)p;
}
#define MFMA(a, b, c) __builtin_amdgcn_mfma_f32_16x16x32_bf16((a), (b), (c), 0, 0, 0)
#define LOG2E 1.4426950408889634f

// ---------------------------------------------------------------------------
// Kernel 1: weight prep. Wcat^T hi/lo bf16 [192][256] (rows 0-31 Wq^T, 32-63
// Wk^T, 64-191 Wv^T), WoT bf16 [256][128].
// ---------------------------------------------------------------------------
__global__ void prep_weights(const float* __restrict__ Wq, const float* __restrict__ Wk,
                             const float* __restrict__ Wv, const float* __restrict__ Wo,
                             unsigned short* __restrict__ Wth, unsigned short* __restrict__ Wtl,
                             unsigned short* __restrict__ WoT) {
  int idx = blockIdx.x * 256 + threadIdx.x;
  if (idx < 192 * 256) {
    int o = idx >> 8, c = idx & 255;
    float w = (o < 32) ? Wq[c * 32 + o] : (o < 64) ? Wk[c * 32 + (o - 32)] : Wv[c * 128 + (o - 64)];
    unsigned short h = f2bf(w);
    Wth[idx] = h;
    Wtl[idx] = f2bf(w - bf2f(h));
  } else if (idx < 192 * 256 + 256 * 128) {
    int j = idx - 192 * 256;
    int c = j >> 7, d = j & 127;
    WoT[j] = f2bf(Wo[d * 256 + c]);
  }
}

// ---------------------------------------------------------------------------
// Kernel 2: QKV projection. 32 pixels/block. q is pre-scaled by log2(e) so the
// flash kernel can use raw v_exp_f32 (exp2) for softmax.
// ---------------------------------------------------------------------------
__global__ __launch_bounds__(256) void proj_qkv(
    const float* __restrict__ x,
    const unsigned short* __restrict__ Wth, const unsigned short* __restrict__ Wtl,
    const float* __restrict__ bq, const float* __restrict__ bk, const float* __restrict__ bv,
    unsigned short* __restrict__ qh, unsigned short* __restrict__ qlo,
    unsigned short* __restrict__ kh, unsigned short* __restrict__ klo,
    unsigned short* __restrict__ Vt) {
  __shared__ unsigned short xsh[32][264];
  __shared__ unsigned short xsl[32][264];
  const int pix0 = blockIdx.x * 32;
  const int b = pix0 >> 12;
  const int nloc0 = pix0 & 4095;
  const int tid = threadIdx.x;

#pragma unroll
  for (int i = 0; i < 8; ++i) {
    int chunk = i * 256 + tid;
    int row = chunk >> 6;
    int c4 = (chunk & 63) * 4;
    float4 v = *(const float4*)(x + (size_t)(pix0 + row) * 256 + c4);
    unsigned short h0 = f2bf(v.x), h1 = f2bf(v.y), h2 = f2bf(v.z), h3 = f2bf(v.w);
    unsigned short l0 = f2bf(v.x - bf2f(h0)), l1 = f2bf(v.y - bf2f(h1));
    unsigned short l2 = f2bf(v.z - bf2f(h2)), l3 = f2bf(v.w - bf2f(h3));
    uint2 hp, lp;
    hp.x = (unsigned int)h0 | ((unsigned int)h1 << 16);
    hp.y = (unsigned int)h2 | ((unsigned int)h3 << 16);
    lp.x = (unsigned int)l0 | ((unsigned int)l1 << 16);
    lp.y = (unsigned int)l2 | ((unsigned int)l3 << 16);
    *(uint2*)&xsh[row][c4] = hp;
    *(uint2*)&xsl[row][c4] = lp;
  }
  __syncthreads();

  const int wave = tid >> 6, lane = tid & 63, l = lane & 15, qd = lane >> 4;
#pragma unroll
  for (int si = 0; si < 3; ++si) {
    const int sub = wave + si * 4;
    const int outc0 = sub * 16;
    if (si == 0) {  // q/k, split precision
      const int outc = outc0 + l;
      const float bias = (outc < 32) ? bq[outc] : bk[outc - 32];
      f32x4 acc[2];
      acc[0] = (f32x4){bias, bias, bias, bias};
      acc[1] = (f32x4){bias, bias, bias, bias};
#pragma unroll
      for (int kc = 0; kc < 8; ++kc) {
        short8 whf = ld8(Wth + (size_t)(outc0 + l) * 256 + kc * 32 + qd * 8);
        short8 wlf = ld8(Wtl + (size_t)(outc0 + l) * 256 + kc * 32 + qd * 8);
#pragma unroll
        for (int m = 0; m < 2; ++m) {
          short8 xhf = ld8(&xsh[m * 16 + l][kc * 32 + qd * 8]);
          short8 xlf = ld8(&xsl[m * 16 + l][kc * 32 + qd * 8]);
          acc[m] = MFMA(xlf, whf, acc[m]);
          acc[m] = MFMA(xhf, wlf, acc[m]);
          acc[m] = MFMA(xhf, whf, acc[m]);
        }
      }
#pragma unroll
      for (int m = 0; m < 2; ++m)
#pragma unroll
        for (int r = 0; r < 4; ++r) {
          const size_t pixel = (size_t)pix0 + m * 16 + 4 * qd + r;
          float val = acc[m][r];
          if (outc < 32) val *= LOG2E;   // exp2-domain softmax
          unsigned short h = f2bf(val);
          unsigned short lo = f2bf(val - bf2f(h));
          if (outc < 32) { qh[pixel * 32 + outc] = h; qlo[pixel * 32 + outc] = lo; }
          else           { kh[pixel * 32 + outc - 32] = h; klo[pixel * 32 + outc - 32] = lo; }
        }
    } else {  // v, transposed output
      const int dv0 = outc0 - 64;
      const float b0 = bv[dv0 + 4 * qd + 0], b1 = bv[dv0 + 4 * qd + 1];
      const float b2 = bv[dv0 + 4 * qd + 2], b3 = bv[dv0 + 4 * qd + 3];
      f32x4 acc[2];
      acc[0] = (f32x4){b0, b1, b2, b3};
      acc[1] = (f32x4){b0, b1, b2, b3};
#pragma unroll
      for (int kc = 0; kc < 8; ++kc) {
        short8 whf = ld8(Wth + (size_t)(outc0 + l) * 256 + kc * 32 + qd * 8);
#pragma unroll
        for (int m = 0; m < 2; ++m) {
          short8 xhf = ld8(&xsh[m * 16 + l][kc * 32 + qd * 8]);
          acc[m] = MFMA(whf, xhf, acc[m]);  // D = Wv^T * x^T  -> Vt layout
        }
      }
#pragma unroll
      for (int m = 0; m < 2; ++m)
#pragma unroll
        for (int r = 0; r < 4; ++r) {
          int dv = dv0 + 4 * qd + r;
          int n = nloc0 + m * 16 + l;
          Vt[(size_t)b * 128 * 4096 + (size_t)dv * 4096 + n] = f2bf(acc[m][r]);
        }
    }
  }
}

// ---------------------------------------------------------------------------
// Kernel 3: flash attention, SPLIT-K x4. 1024 blocks (batch=blockIdx&7 ->
// XCD-pinned L2). 128 queries x 1024 keys per block. NO VGPR cap: 136 VGPRs
// -> 3 blocks/CU resident (R2's (256,4) cap spilled: 670 MB scratch traffic).
// Writes unnormalized O-partials (bf16) into d_out scratch + (m,l) stats.
// ---------------------------------------------------------------------------
__global__ __launch_bounds__(256) void flash_attn(
    const unsigned short* __restrict__ qh, const unsigned short* __restrict__ qlo,
    const unsigned short* __restrict__ kh, const unsigned short* __restrict__ klo,
    const unsigned short* __restrict__ Vt, unsigned short* __restrict__ opart,
    float* __restrict__ mstat, float* __restrict__ lstat) {
  const int b = blockIdx.x & 7;
  const int r7 = blockIdx.x >> 3;      // 0..127
  const int tile = r7 & 31;            // 0..31
  const int split = r7 >> 5;           // 0..3
  const int wave = threadIdx.x >> 6;
  const int lane = threadIdx.x & 63;
  const int l = lane & 15;
  const int qd = lane >> 4;
  const int m0 = tile * 128 + wave * 32;
  const unsigned short* qh_b = qh + (size_t)b * 4096 * 32;
  const unsigned short* ql_b = qlo + (size_t)b * 4096 * 32;
  const unsigned short* kh_b = kh + (size_t)b * 4096 * 32;
  const unsigned short* kl_b = klo + (size_t)b * 4096 * 32;
  const unsigned short* vt_b = Vt + (size_t)b * 128 * 4096;

  short8 qhf[2], qlf[2];
#pragma unroll
  for (int t = 0; t < 2; ++t) {
    int row = m0 + t * 16 + l;
    qhf[t] = ld8(qh_b + (size_t)row * 32 + qd * 8);
    qlf[t] = ld8(ql_b + (size_t)row * 32 + qd * 8);
  }
  f32x4 acc[2][8];
#pragma unroll
  for (int t = 0; t < 2; ++t)
#pragma unroll
    for (int s = 0; s < 8; ++s) acc[t][s] = (f32x4){0.f, 0.f, 0.f, 0.f};
  float mrun[2] = {-1e30f, -1e30f};
  float lrun[2] = {0.f, 0.f};

  const int srcA = ((qd & 1) * 2) * 16 + l;
  const int srcB = srcA + 16;
  const bool hisel = (qd >> 1) != 0;

#pragma unroll 1
  for (int it = 0; it < 16; ++it) {
    const int n0 = split * 1024 + it * 64;
    short8 khf[4], klf[4];
#pragma unroll
    for (int s = 0; s < 4; ++s) {
      int row = n0 + s * 16 + l;
      khf[s] = ld8(kh_b + (size_t)row * 32 + qd * 8);
      klf[s] = ld8(kl_b + (size_t)row * 32 + qd * 8);
    }
    short8 pfrag[2][2];
#pragma unroll
    for (int t = 0; t < 2; ++t) {
      f32x4 s4[4];
#pragma unroll
      for (int s = 0; s < 4; ++s) {
        f32x4 z = (f32x4){0.f, 0.f, 0.f, 0.f};
        z = MFMA(klf[s], qhf[t], z);   // k_lo * q_hi
        z = MFMA(khf[s], qlf[t], z);   // k_hi * q_lo
        z = MFMA(khf[s], qhf[t], z);   // k_hi * q_hi
        s4[s] = z;                     // S^T: lane holds (n = n0+s*16+4qd+r, m = l)
      }
      float mx = -1e30f;
#pragma unroll
      for (int s = 0; s < 4; ++s)
#pragma unroll
        for (int r = 0; r < 4; ++r) mx = fmaxf(mx, s4[s][r]);
      mx = fmaxf(mx, __shfl_xor(mx, 16));
      mx = fmaxf(mx, __shfl_xor(mx, 32));
      const float mnew = fmaxf(mrun[t], mx);
      float rs = 0.f;
      unsigned int pp[4][2];
#pragma unroll
      for (int s = 0; s < 4; ++s) {
        float p0 = __builtin_amdgcn_exp2f(s4[s][0] - mnew);
        float p1 = __builtin_amdgcn_exp2f(s4[s][1] - mnew);
        float p2 = __builtin_amdgcn_exp2f(s4[s][2] - mnew);
        float p3 = __builtin_amdgcn_exp2f(s4[s][3] - mnew);
        rs += (p0 + p1) + (p2 + p3);
        pp[s][0] = pkbf(p0, p1);
        pp[s][1] = pkbf(p2, p3);
      }
      rs += __shfl_xor(rs, 16);
      rs += __shfl_xor(rs, 32);
      const float alpha = __builtin_amdgcn_exp2f(mrun[t] - mnew);
      lrun[t] = lrun[t] * alpha + rs;
      mrun[t] = mnew;
#pragma unroll
      for (int s = 0; s < 8; ++s)
#pragma unroll
        for (int r = 0; r < 4; ++r) acc[t][s][r] *= alpha;
      // Assemble P^T B-frags: lane needs P(m=l, key=32c+qd*8+j), packed bf16x2.
#pragma unroll
      for (int c = 0; c < 2; ++c) {
        unsigned int a00 = (unsigned int)__shfl((int)pp[2 * c][0], srcA);
        unsigned int a01 = (unsigned int)__shfl((int)pp[2 * c][1], srcA);
        unsigned int b00 = (unsigned int)__shfl((int)pp[2 * c + 1][0], srcA);
        unsigned int b01 = (unsigned int)__shfl((int)pp[2 * c + 1][1], srcA);
        unsigned int a10 = (unsigned int)__shfl((int)pp[2 * c][0], srcB);
        unsigned int a11 = (unsigned int)__shfl((int)pp[2 * c][1], srcB);
        unsigned int b10 = (unsigned int)__shfl((int)pp[2 * c + 1][0], srcB);
        unsigned int b11 = (unsigned int)__shfl((int)pp[2 * c + 1][1], srcB);
        union { unsigned int u[4]; short8 v; } cv;
        cv.u[0] = hisel ? b00 : a00;
        cv.u[1] = hisel ? b01 : a01;
        cv.u[2] = hisel ? b10 : a10;
        cv.u[3] = hisel ? b11 : a11;
        pfrag[t][c] = cv.v;
      }
    }
#pragma unroll
    for (int s = 0; s < 8; ++s) {
      const unsigned short* vr = vt_b + (size_t)(s * 16 + l) * 4096 + n0 + qd * 8;
      short8 v0 = ld8(vr);
      short8 v1 = ld8(vr + 32);
      acc[0][s] = MFMA(v0, pfrag[0][0], acc[0][s]);
      acc[0][s] = MFMA(v1, pfrag[0][1], acc[0][s]);
      acc[1][s] = MFMA(v0, pfrag[1][0], acc[1][s]);
      acc[1][s] = MFMA(v1, pfrag[1][1], acc[1][s]);
    }
  }
  // Epilogue: unnormalized partials + stats.
#pragma unroll
  for (int t = 0; t < 2; ++t) {
    const int row = b * 4096 + m0 + t * 16 + l;
    const size_t obase = ((size_t)split * 32768 + row) * 128;
#pragma unroll
    for (int s = 0; s < 8; ++s) {
      uint2 pkt;
      pkt.x = pkbf(acc[t][s][0], acc[t][s][1]);
      pkt.y = pkbf(acc[t][s][2], acc[t][s][3]);
      *(uint2*)(opart + obase + s * 16 + qd * 4) = pkt;
    }
    if (qd == 0) {
      mstat[split * 32768 + row] = mrun[t];
      lstat[split * 32768 + row] = lrun[t];
    }
  }
}

// ---------------------------------------------------------------------------
// Kernel 3b: combine split-K partials -> normalized attn output ao (bf16).
// ---------------------------------------------------------------------------
__global__ __launch_bounds__(256) void combine_splits(
    const unsigned short* __restrict__ opart, const float* __restrict__ mstat,
    const float* __restrict__ lstat, unsigned short* __restrict__ ao) {
  const int tid = threadIdx.x;
  const int row = blockIdx.x * 16 + (tid >> 4);
  const int col = (tid & 15) * 8;
  float m0 = mstat[row], m1 = mstat[32768 + row];
  float m2 = mstat[65536 + row], m3 = mstat[98304 + row];
  float M = fmaxf(fmaxf(m0, m1), fmaxf(m2, m3));
  float w[4];
  w[0] = __builtin_amdgcn_exp2f(m0 - M);
  w[1] = __builtin_amdgcn_exp2f(m1 - M);
  w[2] = __builtin_amdgcn_exp2f(m2 - M);
  w[3] = __builtin_amdgcn_exp2f(m3 - M);
  float den = w[0] * lstat[row] + w[1] * lstat[32768 + row] +
              w[2] * lstat[65536 + row] + w[3] * lstat[98304 + row];
  float inv = 1.f / den;
  float o[8] = {0.f, 0.f, 0.f, 0.f, 0.f, 0.f, 0.f, 0.f};
#pragma unroll
  for (int s = 0; s < 4; ++s) {
    uint4 v = *(const uint4*)(opart + ((size_t)s * 32768 + row) * 128 + col);
    unsigned int uu[4] = {v.x, v.y, v.z, v.w};
#pragma unroll
    for (int j = 0; j < 4; ++j) {
      o[2 * j]     += w[s] * bf2f((unsigned short)(uu[j] & 0xffff));
      o[2 * j + 1] += w[s] * bf2f((unsigned short)(uu[j] >> 16));
    }
  }
  uint4 outv;
  outv.x = pkbf(o[0] * inv, o[1] * inv);
  outv.y = pkbf(o[2] * inv, o[3] * inv);
  outv.z = pkbf(o[4] * inv, o[5] * inv);
  outv.w = pkbf(o[6] * inv, o[7] * inv);
  *(uint4*)(ao + (size_t)row * 128 + col) = outv;
}

// ---------------------------------------------------------------------------
// Kernel 4: output projection + bias + residual. out = ao @ Wo + bo + x.
// ---------------------------------------------------------------------------
__global__ __launch_bounds__(256) void out_proj(
    const unsigned short* __restrict__ ao, const unsigned short* __restrict__ WoT,
    const float* __restrict__ bo, const float* __restrict__ x, float* __restrict__ out) {
  const int pix0 = blockIdx.x * 64;
  const int wave = threadIdx.x >> 6, lane = threadIdx.x & 63, l = lane & 15, qd = lane >> 4;
  const int base = pix0 + wave * 16;
  short8 af[4];
#pragma unroll
  for (int kc = 0; kc < 4; ++kc)
    af[kc] = ld8(ao + (size_t)(base + l) * 128 + kc * 32 + qd * 8);
#pragma unroll
  for (int sub = 0; sub < 16; ++sub) {
    const int c = sub * 16 + l;
    const float bias = bo[c];
    f32x4 acc = (f32x4){bias, bias, bias, bias};
#pragma unroll
    for (int kc = 0; kc < 4; ++kc) {
      short8 wf = ld8(WoT + (size_t)c * 128 + kc * 32 + qd * 8);
      acc = MFMA(af[kc], wf, acc);
    }
#pragma unroll
    for (int r = 0; r < 4; ++r) {
      const size_t pixel = (size_t)base + 4 * qd + r;
      out[pixel * 256 + c] = acc[r] + x[pixel * 256 + c];
    }
  }
}

// ---------------------------------------------------------------------------
extern "C" void kernel_launch(void* const* d_in, const int* in_sizes, int n_in,
                              void* d_out, int out_size, void* d_ws, size_t ws_size,
                              hipStream_t stream) {
  const float* x  = (const float*)d_in[0];
  const float* Wq = (const float*)d_in[1];
  const float* bq = (const float*)d_in[2];
  const float* Wk = (const float*)d_in[3];
  const float* bk = (const float*)d_in[4];
  const float* Wv = (const float*)d_in[5];
  const float* bv = (const float*)d_in[6];
  const float* Wo = (const float*)d_in[7];
  const float* bo = (const float*)d_in[8];

  char* ws = (char*)d_ws;
  // Workspace map (bytes): total ~26.5 MB
  unsigned short* qh  = (unsigned short*)(ws + 0);          // 2 MB
  unsigned short* qlo = (unsigned short*)(ws + 2097152);    // 2 MB
  unsigned short* kh  = (unsigned short*)(ws + 4194304);    // 2 MB
  unsigned short* klo = (unsigned short*)(ws + 6291456);    // 2 MB
  unsigned short* Vt  = (unsigned short*)(ws + 8388608);    // 8 MB  [8][128][4096]
  unsigned short* ao  = (unsigned short*)(ws + 16777216);   // 8 MB  [32768][128]
  unsigned short* Wth = (unsigned short*)(ws + 25165824);   // 96 KB [192][256]
  unsigned short* Wtl = (unsigned short*)(ws + 25264128);   // 96 KB
  unsigned short* WoT = (unsigned short*)(ws + 25362432);   // 64 KB [256][128]
  float*          mst = (float*)(ws + 25493504);            // 512 KB [4][32768]
  float*          lst = (float*)(ws + 26017792);            // 512 KB [4][32768]
  // O-partials live in d_out used as scratch: [4][32768][128] bf16 = 32 MB,
  // fully overwritten by out_proj at the end (stream-ordered).
  unsigned short* opart = (unsigned short*)d_out;

  prep_weights<<<320, 256, 0, stream>>>(Wq, Wk, Wv, Wo, Wth, Wtl, WoT);
  proj_qkv<<<1024, 256, 0, stream>>>(x, Wth, Wtl, bq, bk, bv, qh, qlo, kh, klo, Vt);
  flash_attn<<<1024, 256, 0, stream>>>(qh, qlo, kh, klo, Vt, opart, mst, lst);
  combine_splits<<<2048, 256, 0, stream>>>(opart, mst, lst, ao);
  out_proj<<<512, 256, 0, stream>>>(ao, WoT, bo, x, (float*)d_out);
}